// Round 5
// baseline (203.944 us; speedup 1.0000x reference)
//
#include <hip/hip_runtime.h>

#define B_    256
#define G_    200
#define S_    100
#define NODE_ 200
#define E_    128
#define H_    8
#define M_    300
#define MT_   19     // m tiles of 16 (304 padded)
#define NT_   13     // n/g tiles of 16 (208 padded)

typedef float    f32x4 __attribute__((ext_vector_type(4)));
typedef short    s16x4 __attribute__((ext_vector_type(4)));
typedef short    s16x8 __attribute__((ext_vector_type(8)));
typedef unsigned u32x4 __attribute__((ext_vector_type(4)));

#define MFMA16(A, B, C) __builtin_amdgcn_mfma_f32_16x16x32_bf16(A, B, C, 0, 0, 0)

#define LOG2E_  1.4426950408889634f
#define CQ_     0.36067376022224085f   // 0.25 * log2e
#define C2T_    0.25503901628148863f   // 2 * (1/sqrt(128)) * log2e
#define C10L_   14.426950408889634f    // 10 * log2e

// ---- split-bf16 helpers ----
__device__ __forceinline__ unsigned bf16u(float x) {
    unsigned u = __builtin_bit_cast(unsigned, x);
    return (u + 0x7fffu + ((u >> 16) & 1u)) >> 16;
}
__device__ __forceinline__ float bfbits(unsigned hb16) {
    return __builtin_bit_cast(float, hb16 << 16);
}
__device__ __forceinline__ short bfhi(float x) { return (short)bf16u(x); }
__device__ __forceinline__ short bflo(float x, short hi) {
    float hf = __builtin_bit_cast(float, ((unsigned)(unsigned short)hi) << 16);
    return (short)bf16u(x - hf);
}
__device__ __forceinline__ unsigned cvtpk(float a, float b) {
    unsigned r;
    asm("v_cvt_pk_bf16_f32 %0, %1, %2" : "=v"(r) : "v"(a), "v"(b));
    return r;
}
__device__ __forceinline__ float exp2a(float x) {   // 2^x via v_exp_f32
    float r;
    asm("v_exp_f32 %0, %1" : "=v"(r) : "v"(x));
    return r;
}
__device__ __forceinline__ s16x8 cat8(s16x4 a, s16x4 b) {
    s16x8 r; r[0]=a[0]; r[1]=a[1]; r[2]=a[2]; r[3]=a[3];
             r[4]=b[0]; r[5]=b[1]; r[6]=b[2]; r[7]=b[3]; return r;
}
__device__ __forceinline__ f32x4 max4(f32x4 a, f32x4 b) {
    f32x4 r; r[0]=fmaxf(a[0],b[0]); r[1]=fmaxf(a[1],b[1]);
             r[2]=fmaxf(a[2],b[2]); r[3]=fmaxf(a[3],b[3]); return r;
}
// pack f32x4 -> two interleaved B-fragments {hi,lo} and {lo,hi}
__device__ __forceinline__ void split_pack(f32x4 v, s16x8& B1, s16x8& B2) {
    unsigned h01 = cvtpk(v[0], v[1]);
    unsigned h23 = cvtpk(v[2], v[3]);
    float e0 = v[0] - __builtin_bit_cast(float, h01 << 16);
    float e1 = v[1] - __builtin_bit_cast(float, h01 & 0xffff0000u);
    float e2 = v[2] - __builtin_bit_cast(float, h23 << 16);
    float e3 = v[3] - __builtin_bit_cast(float, h23 & 0xffff0000u);
    unsigned l01 = cvtpk(e0, e1), l23 = cvtpk(e2, e3);
    u32x4 w1 = {h01, h23, l01, l23};
    u32x4 w2 = {l01, l23, h01, h23};
    B1 = __builtin_bit_cast(s16x8, w1);
    B2 = __builtin_bit_cast(s16x8, w2);
}
// pack two f32x4 (K-halves) -> full-K {hi} and {lo} B-fragments
__device__ __forceinline__ void pack8(f32x4 a0, f32x4 a1, s16x8& Bh, s16x8& Bl) {
    unsigned ha = cvtpk(a0[0], a0[1]), hb = cvtpk(a0[2], a0[3]);
    unsigned hc = cvtpk(a1[0], a1[1]), hd = cvtpk(a1[2], a1[3]);
    float e0 = a0[0] - __builtin_bit_cast(float, ha << 16);
    float e1 = a0[1] - __builtin_bit_cast(float, ha & 0xffff0000u);
    float e2 = a0[2] - __builtin_bit_cast(float, hb << 16);
    float e3 = a0[3] - __builtin_bit_cast(float, hb & 0xffff0000u);
    float e4 = a1[0] - __builtin_bit_cast(float, hc << 16);
    float e5 = a1[1] - __builtin_bit_cast(float, hc & 0xffff0000u);
    float e6 = a1[2] - __builtin_bit_cast(float, hd << 16);
    float e7 = a1[3] - __builtin_bit_cast(float, hd & 0xffff0000u);
    unsigned la = cvtpk(e0, e1), lb = cvtpk(e2, e3);
    unsigned lc = cvtpk(e4, e5), ld = cvtpk(e6, e7);
    u32x4 wh = {ha, hb, hc, hd}, wl = {la, lb, lc, ld};
    Bh = __builtin_bit_cast(s16x8, wh);
    Bl = __builtin_bit_cast(s16x8, wl);
}

// =================== setup: W fragments ===================
__global__ __launch_bounds__(64) void wfrag_kernel(
    const float* __restrict__ Wk, const float* __restrict__ Wv,
    const float* __restrict__ Wl, const float* __restrict__ Wc,
    short* __restrict__ wf8_hi, short* __restrict__ wf8_lo)
{
    const int p = blockIdx.x, ct = blockIdx.y;
    const int l = threadIdx.x, qq = l >> 4, li = l & 15;
    const float* W = (p == 0) ? Wk : ((p == 1) ? Wv : ((p == 2) ? Wl : Wc));
    for (int kc = 0; kc < 8; ++kc) {
        s16x4 hi, lo;
        #pragma unroll
        for (int j = 0; j < 4; ++j) {
            float v = W[(kc*16 + qq*4 + j)*E_ + ct*16 + li];
            short h = bfhi(v); hi[j] = h; lo[j] = bflo(v, h);
        }
        const int ix = (((p*8 + ct)*4 + (kc >> 1))*64 + l)*8 + (kc & 1)*4;
        *(s16x4*)(wf8_hi + ix) = hi;
        *(s16x4*)(wf8_lo + ix) = lo;
    }
}

// =================== qbase[b][c] = graph[b] @ Wq[:128] ===================
__global__ __launch_bounds__(128) void qbase_kernel(
    const float* __restrict__ graph, const float* __restrict__ Wq,
    float* __restrict__ qbase)
{
    const int b = blockIdx.x, c = threadIdx.x;
    __shared__ float gs[E_];
    gs[c] = graph[b*E_ + c];
    __syncthreads();
    float acc = 0.f;
    #pragma unroll 8
    for (int e = 0; e < E_; ++e) acc += gs[e] * Wq[e*E_ + c];
    qbase[b*E_ + c] = acc;
}

// =================== proj: k/v/shk fragments ===================
__global__ __launch_bounds__(64, 4) void proj_kernel(
    const float* __restrict__ enc,
    const short* __restrict__ wf8_hi, const short* __restrict__ wf8_lo,
    short* __restrict__ kf_il, short* __restrict__ vf_il,
    short* __restrict__ sf8_hi, short* __restrict__ sf8_lo)
{
    int id = blockIdx.x;
    { const int xcd = id & 7, pos = id >> 3; id = xcd*608 + pos; }
    const int b = id / MT_, mt = id % MT_;
    const int l = threadIdx.x, qq = l >> 4, li = l & 15;
    const int m = mt*16 + li;

    s16x8 Ahi[4], Alo[4];
    #pragma unroll
    for (int u = 0; u < 4; ++u) {
        float va[8];
        if (m < M_) {
            const float* ep = enc + ((size_t)b*M_ + m)*E_ + u*32 + qq*4;
            float4 f0 = *(const float4*)ep;
            float4 f1 = *(const float4*)(ep + 16);
            va[0]=f0.x; va[1]=f0.y; va[2]=f0.z; va[3]=f0.w;
            va[4]=f1.x; va[5]=f1.y; va[6]=f1.z; va[7]=f1.w;
        } else {
            #pragma unroll
            for (int j = 0; j < 8; ++j) va[j] = 0.f;
        }
        #pragma unroll
        for (int j = 0; j < 8; ++j) {
            short h = bfhi(va[j]); Ahi[u][j] = h; Alo[u][j] = bflo(va[j], h);
        }
    }

    __shared__ unsigned tile[16*17];

    #pragma unroll
    for (int p = 0; p < 3; ++p) {
        if (p == 2 && mt >= NT_) break;
        #pragma unroll
        for (int ct = 0; ct < 8; ++ct) {
            f32x4 acc = {0.f, 0.f, 0.f, 0.f};
            #pragma unroll
            for (int u = 0; u < 4; ++u) {
                const int base = (((p*8 + ct)*4 + u)*64 + l)*8;
                s16x8 Bh = *(const s16x8*)(wf8_hi + base);
                s16x8 Bl = *(const s16x8*)(wf8_lo + base);
                acc = MFMA16(Ahi[u], Bh, acc);
                acc = MFMA16(Ahi[u], Bl, acc);
                acc = MFMA16(Alo[u], Bh, acc);
            }
            if (p == 1) {
                s16x4 oh, ol;
                #pragma unroll
                for (int r = 0; r < 4; ++r) { short h = bfhi(acc[r]); oh[r] = h; ol[r] = bflo(acc[r], h); }
                const size_t ix = (((size_t)(b*8 + ct))*MT_ + mt)*512 + (size_t)l*8;
                *(s16x8*)(vf_il + ix) = cat8(oh, ol);
            } else {
                #pragma unroll
                for (int r = 0; r < 4; ++r) {
                    short h = bfhi(acc[r]); short lo = bflo(acc[r], h);
                    tile[(qq*4 + r)*17 + li] = (((unsigned)(unsigned short)h) << 16) | (unsigned short)(unsigned)lo;
                }
                __syncthreads();
                s16x4 oh, ol;
                #pragma unroll
                for (int j = 0; j < 4; ++j) {
                    unsigned wv = tile[li*17 + qq*4 + j];
                    oh[j] = (short)(wv >> 16); ol[j] = (short)(wv & 0xffffu);
                }
                if (p == 0) {
                    const size_t ix = (((size_t)(b*8 + ct))*MT_ + mt)*512 + (size_t)l*8;
                    *(s16x8*)(kf_il + ix) = cat8(oh, ol);
                } else {
                    const size_t ix = (((size_t)(b*NT_ + mt))*4 + (ct >> 1))*512 + (size_t)l*8 + (ct & 1)*4;
                    *(s16x4*)(sf8_hi + ix) = oh;
                    *(s16x4*)(sf8_lo + ix) = ol;
                }
                __syncthreads();
            }
        }
    }
}

// =================== attn: scores+softmax+PV (+fused Wc/logits/softmax) ===================
template <int FUSED>
__global__ __launch_bounds__(256, 3) void attn_fused_kernel(
    const float* __restrict__ capacity, const float* __restrict__ sols_mask,
    const float* __restrict__ ninf_mask, const float* __restrict__ Wq,
    const float* __restrict__ qbase,
    const short* __restrict__ kf_il, const short* __restrict__ vf_il,
    const short* __restrict__ wf8_hi, const short* __restrict__ wf8_lo,
    const short* __restrict__ sf8_hi, const short* __restrict__ sf8_lo,
    const float* __restrict__ bc_,
    float* __restrict__ outws,     // FUSED=0 path
    float* __restrict__ out)       // FUSED=1 path
{
    int id = blockIdx.x;                       // 3328 = 8*416
    { const int xcd = id & 7, pos = id >> 3; id = xcd*416 + pos; }
    const int b = id / NT_, gt = id % NT_;
    const int t = threadIdx.x;
    const int w = t >> 6, l = t & 63, qq = l >> 4, li = l & 15;
    const int g0 = gt*16;

    __shared__ unsigned mlds[MT_][64][2];      // 9728 B: masks pre-scaled by log2e
    __shared__ float out_l[8*64*4];            // 8 KB: attn out, then mh
    __shared__ float zbuf[16*212];             // 13.6 KB: final weights
    __shared__ float ps[64];                   // per-wave per-g partial sums
    __shared__ float rsl[16];

    // ---- coalesced mask fill, pre-scaled by log2e ----
    {
        const size_t bg = (size_t)b*G_;
        for (int f = t; f < 1600; f += 256) {          // ninf: 16 rows x 100 float2
            const int g = f/100, p = f - g*100;
            int gg = g0 + g; gg = (gg < G_) ? gg : G_-1;
            float2 v = *(const float2*)(ninf_mask + (bg + gg)*NODE_ + p*2);
            const int mm = p*2;
            mlds[mm>>4][((mm>>2)&3)*16 + g][(mm>>1)&1] = cvtpk(v.x*LOG2E_, v.y*LOG2E_);
        }
        for (int f = t; f < 800; f += 256) {           // sols: 16 rows x 50 float2
            const int g = f/50, p = f - g*50;
            int gg = g0 + g; gg = (gg < G_) ? gg : G_-1;
            float2 v = *(const float2*)(sols_mask + (bg + gg)*S_ + p*2);
            const int mm = 200 + p*2;
            mlds[mm>>4][((mm>>2)&3)*16 + g][(mm>>1)&1] = cvtpk(v.x*LOG2E_, v.y*LOG2E_);
        }
        if (t < 32) {                                  // pad rows m=300..303 -> -inf
            mlds[18][48 + (t>>1)][t&1] = 0xFF80FF80u;
        }
    }
    __syncthreads();

    int ggl = g0 + li; ggl = (ggl < G_) ? ggl : G_-1;
    const float cap = capacity[b*G_ + ggl];
    const bool isN12 = (qq < 2);               // tile 12 rows m=192..199 are nodes iff qq<2

    #pragma unroll 1
    for (int hi2 = 0; hi2 < 2; ++hi2) {
        const int h = w*2 + hi2;
        // ---- q interleaved B-frags ----
        s16x8 qB1, qB2;
        {
            float4 qb4 = *(const float4*)(qbase + b*E_ + h*16 + qq*4);
            float4 wl4 = *(const float4*)(Wq + E_*E_ + h*16 + qq*4);
            f32x4 qv = {qb4.x + cap*wl4.x, qb4.y + cap*wl4.y,
                        qb4.z + cap*wl4.z, qb4.w + cap*wl4.w};
            split_pack(qv, qB1, qB2);
        }
        // ---- scoresT[m][g] ----
        f32x4 sc[MT_];
        const size_t kb = ((size_t)(b*8 + h)*MT_)*512 + (size_t)l*8;
        #pragma unroll
        for (int mt = 0; mt < MT_; ++mt) {
            s16x8 kf8 = *(const s16x8*)(kf_il + kb + (size_t)mt*512);
            f32x4 a = {0.f, 0.f, 0.f, 0.f};
            a = MFMA16(kf8, qB1, a);
            a = MFMA16(kf8, qB2, a);
            sc[mt] = a;
        }
        // ---- no-max softmax: e = exp2(s*CQ + mask*log2e); segmented sums ----
        f32x4 sA = {0.f,0.f,0.f,0.f}, sB = {0.f,0.f,0.f,0.f}, sC = {0.f,0.f,0.f,0.f};
        #pragma unroll
        for (int mt = 0; mt < MT_; ++mt) {
            const uint2 mp = *(const uint2*)&mlds[mt][l][0];
            f32x4 e;
            e[0] = exp2a(fmaf(sc[mt][0], CQ_, bfbits(mp.x & 0xffffu)));
            e[1] = exp2a(fmaf(sc[mt][1], CQ_, bfbits(mp.x >> 16)));
            e[2] = exp2a(fmaf(sc[mt][2], CQ_, bfbits(mp.y & 0xffffu)));
            e[3] = exp2a(fmaf(sc[mt][3], CQ_, bfbits(mp.y >> 16)));
            sc[mt] = e;
            if (mt < 12)       { if (mt & 1) sB += e; else sA += e; }
            else if (mt > 12)  sC += e;
        }
        float s12 = (sc[12][0] + sc[12][1]) + (sc[12][2] + sc[12][3]);
        f32x4 sAB = sA + sB;
        float sN = (sAB[0] + sAB[1]) + (sAB[2] + sAB[3]) + (isN12 ? s12 : 0.f);
        float sS = (sC[0] + sC[1]) + (sC[2] + sC[3]) + (isN12 ? 0.f : s12);
        sN += __shfl_xor(sN, 16); sN += __shfl_xor(sN, 32);
        sS += __shfl_xor(sS, 16); sS += __shfl_xor(sS, 32);
        const float rN = 1.f / sN, rS = 1.f / sS;
        { const float r12 = isN12 ? rN : rS; sc[12] *= r12; }   // tile 12 pre-normalized

        // ---- PV with deferred normalization (segmented accumulators) ----
        f32x4 oN0 = {0.f,0.f,0.f,0.f}, oN1 = {0.f,0.f,0.f,0.f};
        f32x4 oS0 = {0.f,0.f,0.f,0.f}, oS1 = {0.f,0.f,0.f,0.f};
        f32x4 o12 = {0.f,0.f,0.f,0.f};
        #pragma unroll
        for (int mt = 0; mt < MT_; ++mt) {
            s16x8 pB1, pB2;
            split_pack(sc[mt], pB1, pB2);
            s16x8 vf8 = *(const s16x8*)(vf_il + kb + (size_t)mt*512);
            f32x4& acc = (mt < 12) ? ((mt & 1) ? oN1 : oN0)
                       : (mt == 12 ? o12 : ((mt & 1) ? oS1 : oS0));
            acc = MFMA16(vf8, pB1, acc);
            acc = MFMA16(vf8, pB2, acc);
        }
        f32x4 on = oN0 + oN1, os = oS0 + oS1, osum;
        #pragma unroll
        for (int r = 0; r < 4; ++r)
            osum[r] = fmaf(on[r], rN, fmaf(os[r], rS, o12[r]));

        if (FUSED) {
            *(f32x4*)(out_l + (h*64 + l)*4) = osum;
        } else {
            *(f32x4*)(outws + (((size_t)(b*NT_ + gt))*8 + h)*256 + (size_t)l*4) = osum;
        }
    }

    if constexpr (FUSED) {
        __syncthreads();
        // ---- phase A: Wc GEMM (2 jt per wave) ----
        s16x8 BhO[4], BlO[4];
        #pragma unroll
        for (int u = 0; u < 4; ++u) {
            f32x4 a0 = *(const f32x4*)(out_l + ((2*u)*64 + l)*4);
            f32x4 a1 = *(const f32x4*)(out_l + ((2*u + 1)*64 + l)*4);
            pack8(a0, a1, BhO[u], BlO[u]);
        }
        f32x4 mh01[2];
        #pragma unroll
        for (int half = 0; half < 2; ++half) {
            const int jt = w*2 + half;
            f32x4 acc = {0.f, 0.f, 0.f, 0.f};
            #pragma unroll
            for (int uu = 0; uu < 4; ++uu) {
                const int base = (((3*8 + jt)*4 + uu)*64 + l)*8;
                s16x8 Ah = *(const s16x8*)(wf8_hi + base);
                s16x8 Al = *(const s16x8*)(wf8_lo + base);
                acc = MFMA16(Ah, BhO[uu], acc);
                acc = MFMA16(Ah, BlO[uu], acc);
                acc = MFMA16(Al, BhO[uu], acc);
            }
            float4 b4 = *(const float4*)(bc_ + jt*16 + qq*4);
            acc[0] += b4.x; acc[1] += b4.y; acc[2] += b4.z; acc[3] += b4.w;
            mh01[half] = acc;
        }
        __syncthreads();                       // all reads of out_l done
        *(f32x4*)(out_l + ((w*2)*64 + l)*4)     = mh01[0];
        *(f32x4*)(out_l + ((w*2 + 1)*64 + l)*4) = mh01[1];
        __syncthreads();

        // ---- phase B: final logits GEMM (3-4 nt per wave) + tanh + exp2 ----
        s16x8 Bh2[4], Bl2[4];
        #pragma unroll
        for (int u = 0; u < 4; ++u) {
            f32x4 m0 = *(const f32x4*)(out_l + ((2*u)*64 + l)*4);
            f32x4 m1 = *(const f32x4*)(out_l + ((2*u + 1)*64 + l)*4);
            pack8(m0, m1, Bh2[u], Bl2[u]);
        }
        float psum = 0.f;
        for (int i = 0; i < 4; ++i) {
            const int nt = w + 4*i;
            if (nt >= NT_) break;              // wave-uniform
            f32x4 acc = {0.f, 0.f, 0.f, 0.f};
            #pragma unroll
            for (int u = 0; u < 4; ++u) {
                const size_t base = (((size_t)(b*NT_ + nt))*4 + u)*512 + (size_t)l*8;
                s16x8 Ah = *(const s16x8*)(sf8_hi + base);
                s16x8 Al = *(const s16x8*)(sf8_lo + base);
                acc = MFMA16(Ah, Bh2[u], acc);
                acc = MFMA16(Ah, Bl2[u], acc);
                acc = MFMA16(Al, Bh2[u], acc);
            }
            const uint2 mp = *(const uint2*)&mlds[nt][l][0];
            f32x4 ev;
            {
                float ex0 = exp2a(acc[0]*C2T_), ex1 = exp2a(acc[1]*C2T_);
                float ex2 = exp2a(acc[2]*C2T_), ex3 = exp2a(acc[3]*C2T_);
                float th0 = 1.f - 2.f/(ex0 + 1.f), th1 = 1.f - 2.f/(ex1 + 1.f);
                float th2 = 1.f - 2.f/(ex2 + 1.f), th3 = 1.f - 2.f/(ex3 + 1.f);
                ev[0] = exp2a(fmaf(th0, C10L_, bfbits(mp.x & 0xffffu)));
                ev[1] = exp2a(fmaf(th1, C10L_, bfbits(mp.x >> 16)));
                ev[2] = exp2a(fmaf(th2, C10L_, bfbits(mp.y & 0xffffu)));
                ev[3] = exp2a(fmaf(th3, C10L_, bfbits(mp.y >> 16)));
            }
            if (nt == 12 && qq >= 2) { ev[0]=0.f; ev[1]=0.f; ev[2]=0.f; ev[3]=0.f; }
            *(f32x4*)(zbuf + li*212 + nt*16 + qq*4) = ev;
            psum += (ev[0] + ev[1]) + (ev[2] + ev[3]);
        }
        psum += __shfl_xor(psum, 16); psum += __shfl_xor(psum, 32);
        if (qq == 0) ps[w*16 + li] = psum;
        __syncthreads();
        if (t < 16) rsl[t] = 1.f / (ps[t] + ps[16 + t] + ps[32 + t] + ps[48 + t]);
        __syncthreads();

        // ---- coalesced final store ----
        float* ob = out + ((size_t)b*G_ + g0)*NODE_;
        for (int g2 = 0; g2 < 16; ++g2) {
            if (g0 + g2 < G_ && t < NODE_)
                ob[(size_t)g2*NODE_ + t] = zbuf[g2*212 + t] * rsl[g2];
        }
    }
}

// =================== attn2 (fallback path, proven R4 code) ===================
__global__ __launch_bounds__(64, 4) void attn2_kernel(
    const float* __restrict__ ninf_mask,
    const short* __restrict__ sf8_hi, const short* __restrict__ sf8_lo,
    const short* __restrict__ wf8_hi, const short* __restrict__ wf8_lo,
    const float* __restrict__ bc_,
    const float* __restrict__ outws,
    float* __restrict__ out)
{
    int id = blockIdx.x;
    { const int xcd = id & 7, pos = id >> 3; id = xcd*416 + pos; }
    const int b = id / NT_, gt = id % NT_;
    const int l = threadIdx.x, qq = l >> 4, li = l & 15;
    const int g0 = gt*16;

    __shared__ float pool[16*308];

    {
        const size_t bg = (size_t)b*G_;
        for (int f = l; f < 800; f += 64) {
            const int g = f/50, p = f - g*50;
            int gg = g0 + g; gg = (gg < G_) ? gg : G_-1;
            *(float4*)&pool[g*308 + p*4] = *(const float4*)(ninf_mask + (bg + gg)*NODE_ + p*4);
        }
    }
    __syncthreads();

    s16x8 BhO[4], BlO[4];
    #pragma unroll
    for (int u = 0; u < 4; ++u) {
        f32x4 a0 = *(const f32x4*)(outws + (((size_t)(b*NT_ + gt))*8 + 2*u)*256 + (size_t)l*4);
        f32x4 a1 = *(const f32x4*)(outws + (((size_t)(b*NT_ + gt))*8 + 2*u + 1)*256 + (size_t)l*4);
        pack8(a0, a1, BhO[u], BlO[u]);
    }
    s16x8 Bh2[4], Bl2[4];
    #pragma unroll
    for (int u = 0; u < 4; ++u) {
        f32x4 t01[2];
        #pragma unroll
        for (int half = 0; half < 2; ++half) {
            const int jt = 2*u + half;
            f32x4 acc = {0.f, 0.f, 0.f, 0.f};
            #pragma unroll
            for (int uu = 0; uu < 4; ++uu) {
                const int base = (((3*8 + jt)*4 + uu)*64 + l)*8;
                s16x8 Ah = *(const s16x8*)(wf8_hi + base);
                s16x8 Al = *(const s16x8*)(wf8_lo + base);
                acc = MFMA16(Ah, BhO[uu], acc);
                acc = MFMA16(Ah, BlO[uu], acc);
                acc = MFMA16(Al, BhO[uu], acc);
            }
            float4 b4 = *(const float4*)(bc_ + jt*16 + qq*4);
            acc[0] += b4.x; acc[1] += b4.y; acc[2] += b4.z; acc[3] += b4.w;
            t01[half] = acc;
        }
        pack8(t01[0], t01[1], Bh2[u], Bl2[u]);
    }
    f32x4 z[NT_];
    #pragma unroll
    for (int nt = 0; nt < NT_; ++nt) {
        f32x4 acc = {0.f, 0.f, 0.f, 0.f};
        #pragma unroll
        for (int u = 0; u < 4; ++u) {
            const size_t base = (((size_t)(b*NT_ + nt))*4 + u)*512 + (size_t)l*8;
            s16x8 Ah = *(const s16x8*)(sf8_hi + base);
            s16x8 Al = *(const s16x8*)(sf8_lo + base);
            acc = MFMA16(Ah, Bh2[u], acc);
            acc = MFMA16(Ah, Bl2[u], acc);
            acc = MFMA16(Al, Bh2[u], acc);
        }
        z[nt] = acc;
    }
    const float rE = 0.08838834764831845f;
    #pragma unroll
    for (int nt = 0; nt < NT_; ++nt) {
        f32x4 mk = *(const f32x4*)&pool[li*308 + nt*16 + qq*4];
        #pragma unroll
        for (int r = 0; r < 4; ++r) {
            float lg;
            if (nt < 12 || (qq*4 + r) < 8) {
                float a2 = z[nt][r] * rE;
                float ex = __expf(2.f * a2);
                float th = 1.f - 2.f / (ex + 1.f);
                lg = 10.f*th + mk[r];
            } else lg = -3.0e38f;
            z[nt][r] = lg;
        }
    }
    float mx;
    {
        f32x4 m0 = max4(z[0], z[1]),  m1 = max4(z[2], z[3]),  m2 = max4(z[4], z[5]);
        f32x4 m3 = max4(z[6], z[7]),  m4 = max4(z[8], z[9]),  m5 = max4(z[10], z[11]);
        f32x4 mm = max4(max4(max4(m0, m1), max4(m2, m3)), max4(max4(m4, m5), z[12]));
        mx = fmaxf(fmaxf(mm[0], mm[1]), fmaxf(mm[2], mm[3]));
        mx = fmaxf(mx, __shfl_xor(mx, 16)); mx = fmaxf(mx, __shfl_xor(mx, 32));
    }
    float sm;
    {
        f32x4 sA = {0.f,0.f,0.f,0.f}, sB = {0.f,0.f,0.f,0.f};
        #pragma unroll
        for (int nt = 0; nt < 12; nt += 2) {
            f32x4 e0, e1;
            #pragma unroll
            for (int r = 0; r < 4; ++r) { e0[r] = __expf(z[nt][r]   - mx);
                                          e1[r] = __expf(z[nt+1][r] - mx); }
            z[nt] = e0; z[nt+1] = e1; sA += e0; sB += e1;
        }
        f32x4 e;
        #pragma unroll
        for (int r = 0; r < 4; ++r) e[r] = __expf(z[12][r] - mx);
        z[12] = e; sA += e;
        f32x4 sAB = sA + sB;
        sm = (sAB[0] + sAB[1]) + (sAB[2] + sAB[3]);
        sm += __shfl_xor(sm, 16); sm += __shfl_xor(sm, 32);
    }
    const float rs = 1.f / sm;

    float* ob = out + (size_t)b*G_*NODE_;
    __syncthreads();
    #pragma unroll
    for (int ch = 0; ch < 4; ++ch) {
        const int ntn = (ch < 3) ? 4 : 1;
        for (int k = 0; k < ntn; ++k) {
            const int nt = ch*4 + k;
            #pragma unroll
            for (int r = 0; r < 4; ++r)
                pool[li*69 + k*16 + qq*4 + r] = z[nt][r] * rs;
        }
        __syncthreads();
        const int n = ch*64 + l;
        const bool nok = (ch < 3) || (l < 8);
        #pragma unroll
        for (int gi = 0; gi < 16; ++gi) {
            const int g = g0 + gi;
            if (nok && g < G_) ob[(size_t)g*NODE_ + n] = pool[gi*69 + l];
        }
        __syncthreads();
    }
}

// =================== launch ===================
extern "C" void kernel_launch(void* const* d_in, const int* in_sizes, int n_in,
                              void* d_out, int out_size, void* d_ws, size_t ws_size,
                              hipStream_t stream) {
    (void)in_sizes; (void)n_in; (void)out_size;
    const float* graph = (const float*)d_in[0];
    const float* capacity = (const float*)d_in[1];
    const float* sols_mask = (const float*)d_in[2];
    const float* ninf_mask = (const float*)d_in[3];
    const float* enc = (const float*)d_in[4];
    const float* Wq  = (const float*)d_in[5];
    const float* Wk  = (const float*)d_in[6];
    const float* Wv  = (const float*)d_in[7];
    const float* Wc  = (const float*)d_in[8];
    const float* bc  = (const float*)d_in[9];
    const float* Wkl = (const float*)d_in[10];
    float* out = (float*)d_out;

    char* wsb = (char*)d_ws;
    short* kf_il  = (short*)(wsb);                   // 39,845,888
    short* sf8_hi = (short*)(wsb + 39845888);        // 13,631,488
    short* sf8_lo = (short*)(wsb + 53477376);        // 13,631,488
    short* wf8_hi = (short*)(wsb + 67108864);        //    131,072
    short* wf8_lo = (short*)(wsb + 67239936);        //    131,072
    float* qb     = (float*)(wsb + 67371008);        //    131,072
    // fused path: vf in ws (total 107,347,968 B). fallback: vf in d_out, outws in ws.
    const bool fused = (ws_size >= 107347968ull);
    short* vf_il  = fused ? (short*)(wsb + 67502080) : (short*)d_out;
    float* outws  = (float*)(wsb + 67502080);        // 27,262,976 (fallback only)

    wfrag_kernel<<<dim3(4, 8), 64, 0, stream>>>(Wk, Wv, Wkl, Wc, wf8_hi, wf8_lo);
    qbase_kernel<<<B_, 128, 0, stream>>>(graph, Wq, qb);
    proj_kernel<<<MT_*B_, 64, 0, stream>>>(enc, wf8_hi, wf8_lo, kf_il, vf_il, sf8_hi, sf8_lo);
    if (fused) {
        attn_fused_kernel<1><<<NT_*B_, 256, 0, stream>>>(
            capacity, sols_mask, ninf_mask, Wq, qb, kf_il, vf_il,
            wf8_hi, wf8_lo, sf8_hi, sf8_lo, bc, nullptr, out);
    } else {
        attn_fused_kernel<0><<<NT_*B_, 256, 0, stream>>>(
            capacity, sols_mask, ninf_mask, Wq, qb, kf_il, vf_il,
            wf8_hi, wf8_lo, sf8_hi, sf8_lo, bc, outws, nullptr);
        attn2_kernel<<<NT_*B_, 64, 0, stream>>>(ninf_mask, sf8_hi, sf8_lo,
                                                wf8_hi, wf8_lo, bc, outws, out);
    }
}